// Round 6
// baseline (146.337 us; speedup 1.0000x reference)
//
#include <hip/hip_runtime.h>
#include <hip/hip_bf16.h>

// Problem constants
#define BB 64
#define II 1152
#define OO 32
#define DD 8
#define HH 16
#define BOH (BB * OO * HH)    // 32768
#define WTILE (OO * DD * HH)  // 4096 floats per i

// Decomposition: NIC * IC == II. IC=6 -> LDS 36.9 KB -> 3 blocks/CU (12 waves/CU),
// vs R5's IC=9 (38.9 KB but grid 512 = only 2 blocks/CU). Occupancy is the lever.
#define IC   6
#define NIC  192
#define NBB  16    // b per block
#define NBG  4     // b-groups (NBG * NBB == BB)
#define NJB  4     // b per thread
#define WS   132   // padded LDS row stride (breaks 32-way b128 conflicts)

// ---------------------------------------------------------------------------
// Pass kernel: one routing iteration. Grid (NIC, NBG) = 768 blocks x 256 thr
// = 3 blocks/CU. tid = o + 32*hh + 64*bq. Logits are linear in v, so vsum
// (= v0 [+ v1]) replaces any logits array; PASS 0 has uniform coupling 1/32.
// W staged through a 2-buffer LDS pipeline: W[i+1] global loads issue before
// compute on W[i], LDS writes land after compute, one barrier per iteration.
// u for all IC i's staged once up front. Cooperative grid.sync measured
// ~80-100 us/sync on this platform (R4) — kernel boundaries are the barrier.
// ---------------------------------------------------------------------------
template<int PASS, bool ATOMIC>
__global__ __launch_bounds__(256)
void pass_kernel(const float* __restrict__ u, const float* __restrict__ w,
                 const float* __restrict__ pv0, const float* __restrict__ pv1,
                 float* __restrict__ out)
{
    __shared__ float Wsh[2][OO * WS];     // 2 x 16.5 KB double buffer
    __shared__ float Ush[IC * NBB * DD];  // 3 KB: u for all IC i's

    const int tid   = threadIdx.x;
    const int o     = tid & 31;
    const int hh    = (tid >> 5) & 1;
    const int bq    = tid >> 6;           // 0..3
    const int bbase = blockIdx.y * NBB;
    const int i0    = blockIdx.x * IC;
    const int hofs  = hh * 8;

    // One-time u preload: IC*NBB*2 = 192 float4 granules by 256 threads.
    for (int g = tid; g < IC * NBB * 2; g += 256) {
        const int ii = g >> 5;            // g / (NBB*2)
        const int r  = g & 31;
        const int bl = r >> 1;
        const int q4 = (r & 1) * 4;
        *(float4*)&Ush[(ii * NBB + bl) * DD + q4] =
            *(const float4*)(u + ((size_t)(bbase + bl) * II + (i0 + ii)) * DD + q4);
    }

    // vsum = sum of previous v's (constant over i); loads overlap W prologue.
    float vsum[NJB][8];
    if (PASS >= 1) {
        #pragma unroll
        for (int jb = 0; jb < NJB; jb++) {
            const int b = bbase + bq * NJB + jb;
            const float* p = pv0 + ((b * OO + o) * HH + hofs);
            float4 a = *(const float4*)p;
            float4 c = *(const float4*)(p + 4);
            vsum[jb][0] = a.x; vsum[jb][1] = a.y; vsum[jb][2] = a.z; vsum[jb][3] = a.w;
            vsum[jb][4] = c.x; vsum[jb][5] = c.y; vsum[jb][6] = c.z; vsum[jb][7] = c.w;
            if (PASS == 2) {
                const float* q = pv1 + ((b * OO + o) * HH + hofs);
                float4 a2 = *(const float4*)q;
                float4 c2 = *(const float4*)(q + 4);
                vsum[jb][0] += a2.x; vsum[jb][1] += a2.y; vsum[jb][2] += a2.z; vsum[jb][3] += a2.w;
                vsum[jb][4] += c2.x; vsum[jb][5] += c2.y; vsum[jb][6] += c2.z; vsum[jb][7] += c2.w;
            }
        }
    }

    float sacc[NJB][8];
    #pragma unroll
    for (int jb = 0; jb < NJB; jb++)
        #pragma unroll
        for (int h2 = 0; h2 < 8; h2++) sacc[jb][h2] = 0.f;

    // Prologue: stage W[i0] into buffer 0 (1024 float4 chunks, 4/thread).
    {
        const float* wg = w + (size_t)i0 * WTILE;
        #pragma unroll
        for (int j = 0; j < 4; j++) {
            const int c = tid + j * 256;
            float4 v4 = *(const float4*)(wg + c * 4);
            *(float4*)&Wsh[0][(c >> 5) * WS + (c & 31) * 4] = v4;
        }
    }
    __syncthreads();

    for (int ii = 0; ii < IC; ii++) {
        const float* wcur = Wsh[ii & 1];
        const bool pf = (ii + 1 < IC);
        float4 t0, t1, t2, t3;            // W[i+1] in flight during compute
        if (pf) {
            const float* wg = w + (size_t)(i0 + ii + 1) * WTILE;
            t0 = *(const float4*)(wg + (tid      ) * 4);
            t1 = *(const float4*)(wg + (tid + 256) * 4);
            t2 = *(const float4*)(wg + (tid + 512) * 4);
            t3 = *(const float4*)(wg + (tid + 768) * 4);
        }

        // u to registers (broadcast LDS reads; bq wave-uniform)
        float us[NJB][8];
        #pragma unroll
        for (int jb = 0; jb < NJB; jb++) {
            const float* up = &Ush[(ii * NBB + bq * NJB + jb) * DD];
            float4 a = *(const float4*)up;
            float4 c = *(const float4*)(up + 4);
            us[jb][0] = a.x; us[jb][1] = a.y; us[jb][2] = a.z; us[jb][3] = a.w;
            us[jb][4] = c.x; us[jb][5] = c.y; us[jb][6] = c.z; us[jb][7] = c.w;
        }

        // u_hat[b, i, o, h-half] = sum_d u[b,i,d] * W[i,o,d,h]
        float uh[NJB][8];
        #pragma unroll
        for (int jb = 0; jb < NJB; jb++)
            #pragma unroll
            for (int h2 = 0; h2 < 8; h2++) uh[jb][h2] = 0.f;
        #pragma unroll
        for (int d = 0; d < DD; d++) {
            const float* wp = &wcur[o * WS + d * HH + hofs];
            float4 wa = *(const float4*)wp;
            float4 wb = *(const float4*)(wp + 4);
            const float wv[8] = {wa.x, wa.y, wa.z, wa.w, wb.x, wb.y, wb.z, wb.w};
            #pragma unroll
            for (int jb = 0; jb < NJB; jb++)
                #pragma unroll
                for (int h2 = 0; h2 < 8; h2++)
                    uh[jb][h2] = fmaf(us[jb][d], wv[h2], uh[jb][h2]);
        }

        // coupling: softmax over o of (vsum . u_hat); PASS 0 -> uniform 1/32
        float cc[NJB];
        if (PASS == 0) {
            #pragma unroll
            for (int jb = 0; jb < NJB; jb++) cc[jb] = 1.0f / 32.0f;
        } else {
            #pragma unroll
            for (int jb = 0; jb < NJB; jb++) {
                float lg = 0.f;
                #pragma unroll
                for (int h2 = 0; h2 < 8; h2++)
                    lg = fmaf(vsum[jb][h2], uh[jb][h2], lg);
                lg += __shfl_xor(lg, 32, 64);          // combine h-halves
                const float e = __expf(lg);            // |lg| small -> no max-sub
                float se = e;
                #pragma unroll
                for (int off = 16; off >= 1; off >>= 1)
                    se += __shfl_xor(se, off, 64);     // sum over the 32 o-lanes
                cc[jb] = __fdividef(e, se);
            }
        }

        #pragma unroll
        for (int jb = 0; jb < NJB; jb++)
            #pragma unroll
            for (int h2 = 0; h2 < 8; h2++)
                sacc[jb][h2] = fmaf(cc[jb], uh[jb][h2], sacc[jb][h2]);

        // write W[i+1] into the other buffer (vmcnt wait lands here, post-compute)
        if (pf) {
            float* wn = Wsh[(ii + 1) & 1];
            const int c0 = tid, c1 = tid + 256, c2 = tid + 512, c3 = tid + 768;
            *(float4*)&wn[(c0 >> 5) * WS + (c0 & 31) * 4] = t0;
            *(float4*)&wn[(c1 >> 5) * WS + (c1 & 31) * 4] = t1;
            *(float4*)&wn[(c2 >> 5) * WS + (c2 & 31) * 4] = t2;
            *(float4*)&wn[(c3 >> 5) * WS + (c3 & 31) * 4] = t3;
        }
        __syncthreads();
    }

    // emit partial s
    #pragma unroll
    for (int jb = 0; jb < NJB; jb++) {
        const int b = bbase + bq * NJB + jb;
        if (ATOMIC) {
            float* p = out + ((b * OO + o) * HH + hofs);
            #pragma unroll
            for (int h2 = 0; h2 < 8; h2++) atomicAdd(p + h2, sacc[jb][h2]);
        } else {
            // per-chunk slab: fully-covered contiguous lines
            float* p = out + ((size_t)blockIdx.x * BB + b) * (OO * HH) + o * HH + hofs;
            *(float4*)p       = make_float4(sacc[jb][0], sacc[jb][1], sacc[jb][2], sacc[jb][3]);
            *(float4*)(p + 4) = make_float4(sacc[jb][4], sacc[jb][5], sacc[jb][6], sacc[jb][7]);
        }
    }
}

// Fused reduce-over-chunks + squash. 256 blocks x 128 thr = BOH threads;
// t -> (b,o,h), h = t & 15. Consecutive t = consecutive addresses (coalesced);
// unroll 16 keeps 16 loads in flight.
__global__ __launch_bounds__(128)
void reduce_squash_kernel(const float* __restrict__ part, float* __restrict__ v)
{
    const int t = blockIdx.x * 128 + threadIdx.x;   // 0..BOH-1
    float acc = 0.f;
    #pragma unroll 16
    for (int ic = 0; ic < NIC; ic++)
        acc += part[(size_t)ic * BOH + t];
    float sq = acc * acc;
    #pragma unroll
    for (int off = 8; off >= 1; off >>= 1)
        sq += __shfl_xor(sq, off, 16);              // sum over h-group of 16
    const float scale = (sq / (1.f + sq)) * rsqrtf(sq + 1e-8f);
    v[t] = acc * scale;
}

// Standalone squash for the atomic tiny-ws fallback.
__global__ __launch_bounds__(256)
void squash_kernel(const float* __restrict__ s, float* __restrict__ v)
{
    const int t = blockIdx.x * blockDim.x + threadIdx.x;
    if (t >= BB * OO) return;
    const float4* sp = (const float4*)(s + t * HH);
    float4 a = sp[0], b = sp[1], c = sp[2], d = sp[3];
    float sq = a.x*a.x + a.y*a.y + a.z*a.z + a.w*a.w
             + b.x*b.x + b.y*b.y + b.z*b.z + b.w*b.w
             + c.x*c.x + c.y*c.y + c.z*c.z + c.w*c.w
             + d.x*d.x + d.y*d.y + d.z*d.z + d.w*d.w;
    const float scale = (sq / (1.f + sq)) * rsqrtf(sq + 1e-8f);
    a.x *= scale; a.y *= scale; a.z *= scale; a.w *= scale;
    b.x *= scale; b.y *= scale; b.z *= scale; b.w *= scale;
    c.x *= scale; c.y *= scale; c.z *= scale; c.w *= scale;
    d.x *= scale; d.y *= scale; d.z *= scale; d.w *= scale;
    float4* vp = (float4*)(v + t * HH);
    vp[0] = a; vp[1] = b; vp[2] = c; vp[3] = d;
}

extern "C" void kernel_launch(void* const* d_in, const int* in_sizes, int n_in,
                              void* d_out, int out_size, void* d_ws, size_t ws_size,
                              hipStream_t stream)
{
    (void)in_sizes; (void)n_in; (void)out_size;
    const float* u = (const float*)d_in[0];
    const float* w = (const float*)d_in[1];
    float* out = (float*)d_out;

    const size_t need = ((size_t)NIC * BOH + 2 * BOH) * sizeof(float);  // ~25.4 MB
    const dim3 grid(NIC, NBG), blk(256);

    if (ws_size >= need) {
        // 6 dispatches; kernel boundaries are the (cheap) grid barrier.
        float* part = (float*)d_ws;                 // NIC x BOH partial s
        float* v0   = part + (size_t)NIC * BOH;
        float* v1   = v0 + BOH;
        const int rblocks = BOH / 128;              // 256

        pass_kernel<0, false><<<grid, blk, 0, stream>>>(u, w, nullptr, nullptr, part);
        reduce_squash_kernel<<<rblocks, 128, 0, stream>>>(part, v0);
        pass_kernel<1, false><<<grid, blk, 0, stream>>>(u, w, v0, nullptr, part);
        reduce_squash_kernel<<<rblocks, 128, 0, stream>>>(part, v1);
        pass_kernel<2, false><<<grid, blk, 0, stream>>>(u, w, v0, v1, part);
        reduce_squash_kernel<<<rblocks, 128, 0, stream>>>(part, out);
    } else {
        // Tiny-ws fallback: atomic path.
        float* s0 = (float*)d_ws;
        float* s1 = s0 + BOH;
        float* v0 = s1 + BOH;
        float* v1 = v0 + BOH;
        hipMemsetAsync(d_ws, 0, 2 * BOH * sizeof(float), stream);
        hipMemsetAsync(d_out, 0, BOH * sizeof(float), stream);
        const int sq_blocks = (BB * OO + 255) / 256;

        pass_kernel<0, true><<<grid, blk, 0, stream>>>(u, w, nullptr, nullptr, s0);
        squash_kernel<<<sq_blocks, 256, 0, stream>>>(s0, v0);
        pass_kernel<1, true><<<grid, blk, 0, stream>>>(u, w, v0, nullptr, s1);
        squash_kernel<<<sq_blocks, 256, 0, stream>>>(s1, v1);
        pass_kernel<2, true><<<grid, blk, 0, stream>>>(u, w, v0, v1, out);
        squash_kernel<<<sq_blocks, 256, 0, stream>>>(out, out);
    }
}

// Round 7
// 142.128 us; speedup vs baseline: 1.0296x; 1.0296x over previous
//
#include <hip/hip_runtime.h>
#include <hip/hip_bf16.h>

// Problem constants
#define BB 64
#define II 1152
#define OO 32
#define DD 8
#define HH 16
#define BOH (BB * OO * HH)    // 32768
#define WTILE (OO * DD * HH)  // 4096 floats per i

// Decomposition (R5-proven): NIC * IC == II
#define IC   9
#define NIC  128
#define NBB  16    // b per block
#define NBG  4     // b-groups (NBG * NBB == BB)
#define NJB  4     // b per thread
#define WS   132   // padded LDS row stride (breaks 32-way b128 conflicts)

// ---------------------------------------------------------------------------
// DPP rotate-reduce: sum over each 16-lane row, result in every lane of the
// row. Four v_add_f32 with row_ror DPP — VALU pipe, zero DS-pipe traffic.
// ---------------------------------------------------------------------------
__device__ __forceinline__ float row_sum16(float x)
{
    x += __int_as_float(__builtin_amdgcn_update_dpp(
            0, __float_as_int(x), 0x121, 0xF, 0xF, false));  // row_ror:1
    x += __int_as_float(__builtin_amdgcn_update_dpp(
            0, __float_as_int(x), 0x122, 0xF, 0xF, false));  // row_ror:2
    x += __int_as_float(__builtin_amdgcn_update_dpp(
            0, __float_as_int(x), 0x124, 0xF, 0xF, false));  // row_ror:4
    x += __int_as_float(__builtin_amdgcn_update_dpp(
            0, __float_as_int(x), 0x128, 0xF, 0xF, false));  // row_ror:8
    return x;
}

// Sum over 32-lane halves: row_sum16 + one ds_swizzle xor16 (BitMode 0x401F).
__device__ __forceinline__ float o_sum32(float x)
{
    float s = row_sum16(x);
    s += __int_as_float(__builtin_amdgcn_ds_swizzle(__float_as_int(s), 0x401F));
    return s;
}

// ---------------------------------------------------------------------------
// Pass kernel: one routing iteration. Grid (NIC, NBG) = 512 blocks x 256 thr.
// tid = o + 32*hh + 64*bq. Logits are linear in v, so vsum (= v0 [+ v1])
// replaces any logits array; PASS 0 has uniform coupling 1/32.
// DS-pipe diet (R6 analysis: pass kernels are LDS-pipe bound):
//  - W: 16 ds_read_b128/thread/i through a 2-buffer LDS pipeline (W[i+1]
//    global loads issue before compute on W[i]; LDS writes after compute).
//  - u: broadcast GLOBAL loads (all 64 lanes share bq -> same address, L1
//    broadcast, VMEM pipe) — no Ush, no u DS reads.
//  - softmax: 4 DPP row_ror adds (VALU) + 1 swizzle xor16 + 1 shfl xor32
//    per jb instead of a 6-deep DS butterfly.
// Cooperative grid.sync measured ~80-100 us/sync (R4) — kernel boundaries
// are the grid barrier.
// ---------------------------------------------------------------------------
template<int PASS, bool ATOMIC>
__global__ __launch_bounds__(256)
void pass_kernel(const float* __restrict__ u, const float* __restrict__ w,
                 const float* __restrict__ pv0, const float* __restrict__ pv1,
                 float* __restrict__ out)
{
    __shared__ float Wsh[2][OO * WS];     // 2 x 16.5 KB double buffer

    const int tid   = threadIdx.x;
    const int o     = tid & 31;
    const int hh    = (tid >> 5) & 1;
    const int bq    = tid >> 6;           // 0..3
    const int bbase = blockIdx.y * NBB;
    const int i0    = blockIdx.x * IC;
    const int hofs  = hh * 8;

    // vsum = sum of previous v's (constant over i); overlaps W prologue.
    float vsum[NJB][8];
    if (PASS >= 1) {
        #pragma unroll
        for (int jb = 0; jb < NJB; jb++) {
            const int b = bbase + bq * NJB + jb;
            const float* p = pv0 + ((b * OO + o) * HH + hofs);
            float4 a = *(const float4*)p;
            float4 c = *(const float4*)(p + 4);
            vsum[jb][0] = a.x; vsum[jb][1] = a.y; vsum[jb][2] = a.z; vsum[jb][3] = a.w;
            vsum[jb][4] = c.x; vsum[jb][5] = c.y; vsum[jb][6] = c.z; vsum[jb][7] = c.w;
            if (PASS == 2) {
                const float* q = pv1 + ((b * OO + o) * HH + hofs);
                float4 a2 = *(const float4*)q;
                float4 c2 = *(const float4*)(q + 4);
                vsum[jb][0] += a2.x; vsum[jb][1] += a2.y; vsum[jb][2] += a2.z; vsum[jb][3] += a2.w;
                vsum[jb][4] += c2.x; vsum[jb][5] += c2.y; vsum[jb][6] += c2.z; vsum[jb][7] += c2.w;
            }
        }
    }

    float sacc[NJB][8];
    #pragma unroll
    for (int jb = 0; jb < NJB; jb++)
        #pragma unroll
        for (int h2 = 0; h2 < 8; h2++) sacc[jb][h2] = 0.f;

    // Prologue: stage W[i0] into buffer 0 (1024 float4 chunks, 4/thread).
    {
        const float* wg = w + (size_t)i0 * WTILE;
        #pragma unroll
        for (int j = 0; j < 4; j++) {
            const int c = tid + j * 256;
            float4 v4 = *(const float4*)(wg + c * 4);
            *(float4*)&Wsh[0][(c >> 5) * WS + (c & 31) * 4] = v4;
        }
    }
    __syncthreads();

    for (int ii = 0; ii < IC; ii++) {
        const float* wcur = Wsh[ii & 1];
        const bool pf = (ii + 1 < IC);
        float4 t0, t1, t2, t3;            // W[i+1] in flight during compute
        if (pf) {
            const float* wg = w + (size_t)(i0 + ii + 1) * WTILE;
            t0 = *(const float4*)(wg + (tid      ) * 4);
            t1 = *(const float4*)(wg + (tid + 256) * 4);
            t2 = *(const float4*)(wg + (tid + 512) * 4);
            t3 = *(const float4*)(wg + (tid + 768) * 4);
        }

        // u via broadcast global loads: whole wave shares bq -> same address.
        float us[NJB][8];
        #pragma unroll
        for (int jb = 0; jb < NJB; jb++) {
            const float* ub = u + ((size_t)(bbase + bq * NJB + jb) * II + (i0 + ii)) * DD;
            float4 a = *(const float4*)ub;
            float4 c = *(const float4*)(ub + 4);
            us[jb][0] = a.x; us[jb][1] = a.y; us[jb][2] = a.z; us[jb][3] = a.w;
            us[jb][4] = c.x; us[jb][5] = c.y; us[jb][6] = c.z; us[jb][7] = c.w;
        }

        // u_hat[b, i, o, h-half] = sum_d u[b,i,d] * W[i,o,d,h]
        float uh[NJB][8];
        #pragma unroll
        for (int jb = 0; jb < NJB; jb++)
            #pragma unroll
            for (int h2 = 0; h2 < 8; h2++) uh[jb][h2] = 0.f;
        #pragma unroll
        for (int d = 0; d < DD; d++) {
            const float* wp = &wcur[o * WS + d * HH + hofs];
            float4 wa = *(const float4*)wp;
            float4 wb = *(const float4*)(wp + 4);
            const float wv[8] = {wa.x, wa.y, wa.z, wa.w, wb.x, wb.y, wb.z, wb.w};
            #pragma unroll
            for (int jb = 0; jb < NJB; jb++)
                #pragma unroll
                for (int h2 = 0; h2 < 8; h2++)
                    uh[jb][h2] = fmaf(us[jb][d], wv[h2], uh[jb][h2]);
        }

        // coupling: softmax over o of (vsum . u_hat); PASS 0 -> uniform 1/32
        float cc[NJB];
        if (PASS == 0) {
            #pragma unroll
            for (int jb = 0; jb < NJB; jb++) cc[jb] = 1.0f / 32.0f;
        } else {
            #pragma unroll
            for (int jb = 0; jb < NJB; jb++) {
                float lg = 0.f;
                #pragma unroll
                for (int h2 = 0; h2 < 8; h2++)
                    lg = fmaf(vsum[jb][h2], uh[jb][h2], lg);
                lg += __shfl_xor(lg, 32, 64);      // h-half combine (lanes o / o+32 now equal)
                const float e = __expf(lg);        // |lg| small -> no max-sub
                const float se = o_sum32(e);       // sum over 32 o-lanes: 4 DPP + 1 swizzle
                cc[jb] = __fdividef(e, se);
            }
        }

        #pragma unroll
        for (int jb = 0; jb < NJB; jb++)
            #pragma unroll
            for (int h2 = 0; h2 < 8; h2++)
                sacc[jb][h2] = fmaf(cc[jb], uh[jb][h2], sacc[jb][h2]);

        // write W[i+1] into the other buffer (vmcnt wait lands here, post-compute)
        if (pf) {
            float* wn = Wsh[(ii + 1) & 1];
            const int c0 = tid, c1 = tid + 256, c2 = tid + 512, c3 = tid + 768;
            *(float4*)&wn[(c0 >> 5) * WS + (c0 & 31) * 4] = t0;
            *(float4*)&wn[(c1 >> 5) * WS + (c1 & 31) * 4] = t1;
            *(float4*)&wn[(c2 >> 5) * WS + (c2 & 31) * 4] = t2;
            *(float4*)&wn[(c3 >> 5) * WS + (c3 & 31) * 4] = t3;
        }
        __syncthreads();
    }

    // emit partial s
    #pragma unroll
    for (int jb = 0; jb < NJB; jb++) {
        const int b = bbase + bq * NJB + jb;
        if (ATOMIC) {
            float* p = out + ((b * OO + o) * HH + hofs);
            #pragma unroll
            for (int h2 = 0; h2 < 8; h2++) atomicAdd(p + h2, sacc[jb][h2]);
        } else {
            // per-chunk slab: fully-covered contiguous lines
            float* p = out + ((size_t)blockIdx.x * BB + b) * (OO * HH) + o * HH + hofs;
            *(float4*)p       = make_float4(sacc[jb][0], sacc[jb][1], sacc[jb][2], sacc[jb][3]);
            *(float4*)(p + 4) = make_float4(sacc[jb][4], sacc[jb][5], sacc[jb][6], sacc[jb][7]);
        }
    }
}

// Fused reduce-over-chunks + squash. BOH threads; t -> (b,o,h), h = t & 15.
// h-group of 16 = one DPP row -> row_sum16 replaces the shfl butterfly.
__global__ __launch_bounds__(256)
void reduce_squash_kernel(const float* __restrict__ part, float* __restrict__ v)
{
    const int t = blockIdx.x * blockDim.x + threadIdx.x;   // 0..BOH-1
    float acc = 0.f;
    #pragma unroll 16
    for (int ic = 0; ic < NIC; ic++)
        acc += part[(size_t)ic * BOH + t];
    const float sq = row_sum16(acc * acc);                 // sum over h-group (DPP row)
    const float scale = (sq / (1.f + sq)) * rsqrtf(sq + 1e-8f);
    v[t] = acc * scale;
}

// Standalone squash for the atomic tiny-ws fallback.
__global__ __launch_bounds__(256)
void squash_kernel(const float* __restrict__ s, float* __restrict__ v)
{
    const int t = blockIdx.x * blockDim.x + threadIdx.x;
    if (t >= BB * OO) return;
    const float4* sp = (const float4*)(s + t * HH);
    float4 a = sp[0], b = sp[1], c = sp[2], d = sp[3];
    float sq = a.x*a.x + a.y*a.y + a.z*a.z + a.w*a.w
             + b.x*b.x + b.y*b.y + b.z*b.z + b.w*b.w
             + c.x*c.x + c.y*c.y + c.z*c.z + c.w*c.w
             + d.x*d.x + d.y*d.y + d.z*d.z + d.w*d.w;
    const float scale = (sq / (1.f + sq)) * rsqrtf(sq + 1e-8f);
    a.x *= scale; a.y *= scale; a.z *= scale; a.w *= scale;
    b.x *= scale; b.y *= scale; b.z *= scale; b.w *= scale;
    c.x *= scale; c.y *= scale; c.z *= scale; c.w *= scale;
    d.x *= scale; d.y *= scale; d.z *= scale; d.w *= scale;
    float4* vp = (float4*)(v + t * HH);
    vp[0] = a; vp[1] = b; vp[2] = c; vp[3] = d;
}

extern "C" void kernel_launch(void* const* d_in, const int* in_sizes, int n_in,
                              void* d_out, int out_size, void* d_ws, size_t ws_size,
                              hipStream_t stream)
{
    (void)in_sizes; (void)n_in; (void)out_size;
    const float* u = (const float*)d_in[0];
    const float* w = (const float*)d_in[1];
    float* out = (float*)d_out;

    const size_t need = ((size_t)NIC * BOH + 2 * BOH) * sizeof(float);  // ~16.3 MB
    const dim3 grid(NIC, NBG), blk(256);

    if (ws_size >= need) {
        // 6 dispatches; kernel boundaries are the (cheap) grid barrier.
        float* part = (float*)d_ws;                 // NIC x BOH partial s
        float* v0   = part + (size_t)NIC * BOH;
        float* v1   = v0 + BOH;
        const int rblocks = BOH / 256;              // 128

        pass_kernel<0, false><<<grid, blk, 0, stream>>>(u, w, nullptr, nullptr, part);
        reduce_squash_kernel<<<rblocks, 256, 0, stream>>>(part, v0);
        pass_kernel<1, false><<<grid, blk, 0, stream>>>(u, w, v0, nullptr, part);
        reduce_squash_kernel<<<rblocks, 256, 0, stream>>>(part, v1);
        pass_kernel<2, false><<<grid, blk, 0, stream>>>(u, w, v0, v1, part);
        reduce_squash_kernel<<<rblocks, 256, 0, stream>>>(part, out);
    } else {
        // Tiny-ws fallback: atomic path.
        float* s0 = (float*)d_ws;
        float* s1 = s0 + BOH;
        float* v0 = s1 + BOH;
        float* v1 = v0 + BOH;
        hipMemsetAsync(d_ws, 0, 2 * BOH * sizeof(float), stream);
        hipMemsetAsync(d_out, 0, BOH * sizeof(float), stream);
        const int sq_blocks = (BB * OO + 255) / 256;

        pass_kernel<0, true><<<grid, blk, 0, stream>>>(u, w, nullptr, nullptr, s0);
        squash_kernel<<<sq_blocks, 256, 0, stream>>>(s0, v0);
        pass_kernel<1, true><<<grid, blk, 0, stream>>>(u, w, v0, nullptr, s1);
        squash_kernel<<<sq_blocks, 256, 0, stream>>>(s1, v1);
        pass_kernel<2, true><<<grid, blk, 0, stream>>>(u, w, v0, v1, out);
        squash_kernel<<<sq_blocks, 256, 0, stream>>>(out, out);
    }
}